// Round 7
// baseline (483.481 us; speedup 1.0000x reference)
//
#include <hip/hip_runtime.h>

#define SCALE_F 0.08838834764831845f
#define NEG_INF -1e30f

constexpr int S    = 32;
constexpr int Hq   = 32;
constexpr int Hkv  = 8;
constexpr int G    = 4;     // Hq / Hkv
constexpr int D    = 128;
constexpr int BS   = 16;    // kv positions per cache block
constexpr int BMAX = 128;   // max cache blocks per seq
constexpr int KMAX = BMAX * BS;  // 2048

// ---------------------------------------------------------------------------
// Kernel 1: BARRIER-FREE wave-independent partial attention, parts=32.
// One 64-lane wave owns one (s, kv-head, part) item of CHUNKW=64 kv positions.
// No __syncthreads: wave-private LDS slice; compiler lgkmcnt handles same-wave
// ordering, so global loads are never drained by s_barrier vmcnt(0) semantics.
//
// vs round 6: (1) parts 16->32 for finer grain / better CU balance (half the
// parts are inactive at avg seq_len~1024); (2) K-blocks explicitly
// double-buffered in registers (round 6 only batched within a block, leaving
// a full HBM latency exposed at each of the block boundaries).
// ---------------------------------------------------------------------------
template<int PARTS>
__global__ __launch_bounds__(256, 3)
void attn_wave_kernel(const float* __restrict__ q_ptr,
                      const float* __restrict__ kc,
                      const float* __restrict__ vc,
                      const int*   __restrict__ bt,
                      const int*   __restrict__ slens,
                      const float* __restrict__ slopes,
                      float* __restrict__ part_acc,
                      float* __restrict__ part_m,
                      float* __restrict__ part_l)
{
    constexpr int CHUNKW = KMAX / PARTS;   // kv positions per wave item (64)
    constexpr int CPW    = CHUNKW / BS;    // kv cache blocks per item (4)

    __shared__ float sm_p[4][G * CHUNKW];  // per-wave private score/p buffer

    const int wid  = threadIdx.x >> 6;     // wave within block (0..3)
    const int lane = threadIdx.x & 63;
    const int gw   = blockIdx.x * 4 + wid; // global wave-item id
    const int part = gw % PARTS;
    const int sh   = gw / PARTS;           // s*Hkv + h
    const int h    = sh & (Hkv - 1);
    const int s    = sh >> 3;

    const int seq_len   = slens[s];
    const int num_parts = (seq_len + CHUNKW - 1) / CHUNKW;
    if (part >= num_parts) return;         // divergent exit safe: no barriers

    float* smp = sm_p[wid];

    // Block-table entries (valid block ids even beyond seq_len; scores masked).
    int phys[CPW];
    #pragma unroll
    for (int i = 0; i < CPW; ++i) phys[i] = bt[s * BMAX + part * CPW + i];

    const float ctx  = (float)(seq_len - 1);
    const int   pos0 = part * CHUNKW;

    // ---------------- K phase: double-buffered K blocks ----------------
    const int o4 = lane >> 4;   // position-within-quad (0..3)
    const int t  = lane & 15;   // d-chunk index: d = t*8 .. t*8+7

    const float wslope = slopes[h * G + (t & 3)];  // slope for g this lane writes

    float4 qa[G], qb[G];
    #pragma unroll
    for (int g = 0; g < G; ++g) {
        const float* qp = q_ptr + ((size_t)(s * Hq + h * G + g) * D + t * 8);
        qa[g] = ((const float4*)qp)[0];
        qb[g] = ((const float4*)qp)[1];
    }

    float4 kA[2][4], kB[2][4];   // [buf][j2] — 8 float4 per K block
    {
        const float* kbase = kc + ((((size_t)phys[0] * Hkv + h) * (D / 8) + t) * BS) * 8;
        #pragma unroll
        for (int j2 = 0; j2 < 4; ++j2) {
            const float* kp = kbase + (j2 * 4 + o4) * 8;
            kA[0][j2] = ((const float4*)kp)[0];
            kB[0][j2] = ((const float4*)kp)[1];
        }
    }

    #pragma unroll
    for (int i = 0; i < CPW; ++i) {
        const int cb = i & 1;
        if (i + 1 < CPW) {   // issue next K block's 8 loads before consuming
            const float* kbase = kc + ((((size_t)phys[i + 1] * Hkv + h) * (D / 8) + t) * BS) * 8;
            #pragma unroll
            for (int j2 = 0; j2 < 4; ++j2) {
                const float* kp = kbase + (j2 * 4 + o4) * 8;
                kA[cb ^ 1][j2] = ((const float4*)kp)[0];
                kB[cb ^ 1][j2] = ((const float4*)kp)[1];
            }
        }
        #pragma unroll
        for (int j2 = 0; j2 < 4; ++j2) {
            float sc0 = qa[0].x*kA[cb][j2].x + qa[0].y*kA[cb][j2].y + qa[0].z*kA[cb][j2].z + qa[0].w*kA[cb][j2].w
                      + qb[0].x*kB[cb][j2].x + qb[0].y*kB[cb][j2].y + qb[0].z*kB[cb][j2].z + qb[0].w*kB[cb][j2].w;
            float sc1 = qa[1].x*kA[cb][j2].x + qa[1].y*kA[cb][j2].y + qa[1].z*kA[cb][j2].z + qa[1].w*kA[cb][j2].w
                      + qb[1].x*kB[cb][j2].x + qb[1].y*kB[cb][j2].y + qb[1].z*kB[cb][j2].z + qb[1].w*kB[cb][j2].w;
            float sc2 = qa[2].x*kA[cb][j2].x + qa[2].y*kA[cb][j2].y + qa[2].z*kA[cb][j2].z + qa[2].w*kA[cb][j2].w
                      + qb[2].x*kB[cb][j2].x + qb[2].y*kB[cb][j2].y + qb[2].z*kB[cb][j2].z + qb[2].w*kB[cb][j2].w;
            float sc3 = qa[3].x*kA[cb][j2].x + qa[3].y*kA[cb][j2].y + qa[3].z*kA[cb][j2].z + qa[3].w*kA[cb][j2].w
                      + qb[3].x*kB[cb][j2].x + qb[3].y*kB[cb][j2].y + qb[3].z*kB[cb][j2].z + qb[3].w*kB[cb][j2].w;
            #pragma unroll
            for (int msk = 8; msk >= 1; msk >>= 1) {
                sc0 += __shfl_xor(sc0, msk, 16);
                sc1 += __shfl_xor(sc1, msk, 16);
                sc2 += __shfl_xor(sc2, msk, 16);
                sc3 += __shfl_xor(sc3, msk, 16);
            }
            if (t < 4) {
                const int pl   = i * BS + j2 * 4 + o4;   // local pos in chunk
                const int kpos = pos0 + pl;
                const float scv = (t == 0) ? sc0 : (t == 1) ? sc1 : (t == 2) ? sc2 : sc3;
                smp[t * CHUNKW + pl] =
                    (kpos < seq_len) ? (SCALE_F * scv + wslope * ((float)kpos - ctx)) : NEG_INF;
            }
        }
    }

    // ---------------- V prefetch (block 0) — in flight over softmax --------
    const int d0 = lane;                   // covers d = lane and lane + 64
    float4 vreg[2][2][4];                  // [buf][d-half][pos-quad]
    {
        const float* vb = vc + ((size_t)phys[0] * Hkv + h) * D * BS;
        #pragma unroll
        for (int c = 0; c < 4; ++c) {
            vreg[0][0][c] = ((const float4*)(vb + (size_t)d0 * BS))[c];
            vreg[0][1][c] = ((const float4*)(vb + (size_t)(d0 + 64) * BS))[c];
        }
    }

    // ---------------- softmax (LDS + width-16 shuffles, no barrier) --------
    {
        const int gS = lane >> 4;          // g this lane-group reduces
        const int u  = lane & 15;
        float* rowp = smp + gS * CHUNKW;

        float4 sv = ((const float4*)(rowp + u * 4))[0];
        float m = fmaxf(fmaxf(sv.x, sv.y), fmaxf(sv.z, sv.w));
        #pragma unroll
        for (int msk = 8; msk >= 1; msk >>= 1) m = fmaxf(m, __shfl_xor(m, msk, 16));

        float4 pv;
        pv.x = __expf(sv.x - m);
        pv.y = __expf(sv.y - m);
        pv.z = __expf(sv.z - m);
        pv.w = __expf(sv.w - m);
        float l = pv.x + pv.y + pv.z + pv.w;
        ((float4*)(rowp + u * 4))[0] = pv;
        #pragma unroll
        for (int msk = 8; msk >= 1; msk >>= 1) l += __shfl_xor(l, msk, 16);

        if (u == 0) {
            part_m[(sh * PARTS + part) * G + gS] = m;
            part_l[(sh * PARTS + part) * G + gS] = l;
        }
    }

    // ---------------- PV: double-buffered V regs, p via LDS broadcast ------
    float acc0[G] = {0.f, 0.f, 0.f, 0.f};  // d = lane
    float acc1[G] = {0.f, 0.f, 0.f, 0.f};  // d = lane + 64

    #pragma unroll
    for (int i = 0; i < CPW; ++i) {
        const int cb = i & 1;
        if (i + 1 < CPW) {
            const float* vb = vc + ((size_t)phys[i + 1] * Hkv + h) * D * BS;
            #pragma unroll
            for (int c = 0; c < 4; ++c) {
                vreg[cb ^ 1][0][c] = ((const float4*)(vb + (size_t)d0 * BS))[c];
                vreg[cb ^ 1][1][c] = ((const float4*)(vb + (size_t)(d0 + 64) * BS))[c];
            }
        }
        #pragma unroll
        for (int g = 0; g < G; ++g) {
            const float4* pp = (const float4*)(smp + g * CHUNKW + i * BS);
            #pragma unroll
            for (int c = 0; c < 4; ++c) {
                const float4 p4 = pp[c];   // uniform address: LDS broadcast
                acc0[g] += p4.x * vreg[cb][0][c].x + p4.y * vreg[cb][0][c].y
                         + p4.z * vreg[cb][0][c].z + p4.w * vreg[cb][0][c].w;
                acc1[g] += p4.x * vreg[cb][1][c].x + p4.y * vreg[cb][1][c].y
                         + p4.z * vreg[cb][1][c].z + p4.w * vreg[cb][1][c].w;
            }
        }
    }

    float* outp = part_acc + (size_t)(sh * PARTS + part) * G * D;
    #pragma unroll
    for (int g = 0; g < G; ++g) {
        outp[g * D + d0]      = acc0[g];
        outp[g * D + d0 + 64] = acc1[g];
    }
}

// ---------------------------------------------------------------------------
// Kernel 2: combine partials across parts, normalize, write output.
// ---------------------------------------------------------------------------
__global__ __launch_bounds__(512)
void attn_reduce_kernel(const float* __restrict__ part_acc,
                        const float* __restrict__ part_m,
                        const float* __restrict__ part_l,
                        const int*   __restrict__ slens,
                        float* __restrict__ out,
                        int parts, int chunk)
{
    const int sh  = blockIdx.x;      // s*Hkv + h
    const int s   = sh / Hkv;
    const int tid = threadIdx.x;
    const int g   = tid >> 7;
    const int d   = tid & 127;

    const int seq_len = slens[s];
    const int np = min(parts, (seq_len + chunk - 1) / chunk);

    float M = NEG_INF;
    for (int p = 0; p < np; ++p)
        M = fmaxf(M, part_m[(sh * parts + p) * G + g]);
    float L = 0.f, acc = 0.f;
    for (int p = 0; p < np; ++p) {
        const float w = __expf(part_m[(sh * parts + p) * G + g] - M);
        L += w * part_l[(sh * parts + p) * G + g];
        acc += w * part_acc[((size_t)(sh * parts + p) * G + g) * D + d];
    }
    out[(size_t)(sh * G + g) * D + d] = acc / (L + 1e-10f);
}

extern "C" void kernel_launch(void* const* d_in, const int* in_sizes, int n_in,
                              void* d_out, int out_size, void* d_ws, size_t ws_size,
                              hipStream_t stream)
{
    const float* q   = (const float*)d_in[0];
    const float* kc  = (const float*)d_in[1];
    const float* vc  = (const float*)d_in[2];
    const int*   bt  = (const int*)d_in[3];
    const int*   sl  = (const int*)d_in[4];
    const float* slp = (const float*)d_in[5];
    // d_in[6] (query_start_len) is arange(S+1): all rows decode, identity scatter.

    auto ws_need = [](int p) {
        return (size_t)S * Hkv * p * G * (D + 2) * sizeof(float);
    };
    int parts = 32;
    while (parts > 4 && ws_need(parts) > ws_size) parts >>= 1;
    const int chunk = KMAX / parts;

    float* part_acc = (float*)d_ws;
    float* part_m   = part_acc + (size_t)S * Hkv * parts * G * D;
    float* part_l   = part_m   + (size_t)S * Hkv * parts * G;

    const dim3 grid1(S * Hkv * parts / 4);   // 4 wave-items per 256-thread block
    switch (parts) {
    case 32: attn_wave_kernel<32><<<grid1, 256, 0, stream>>>(q, kc, vc, bt, sl, slp, part_acc, part_m, part_l); break;
    case 16: attn_wave_kernel<16><<<grid1, 256, 0, stream>>>(q, kc, vc, bt, sl, slp, part_acc, part_m, part_l); break;
    case 8:  attn_wave_kernel<8> <<<grid1, 256, 0, stream>>>(q, kc, vc, bt, sl, slp, part_acc, part_m, part_l); break;
    default: attn_wave_kernel<4> <<<grid1, 256, 0, stream>>>(q, kc, vc, bt, sl, slp, part_acc, part_m, part_l); break;
    }
    attn_reduce_kernel<<<S * Hkv, 512, 0, stream>>>(
        part_acc, part_m, part_l, sl, (float*)d_out, parts, chunk);
}

// Round 9
// 467.352 us; speedup vs baseline: 1.0345x; 1.0345x over previous
//
#include <hip/hip_runtime.h>

#define SCALE_F 0.08838834764831845f
#define NEG_INF -1e30f

constexpr int S    = 32;
constexpr int Hq   = 32;
constexpr int Hkv  = 8;
constexpr int G    = 4;     // Hq / Hkv
constexpr int D    = 128;
constexpr int BS   = 16;    // kv positions per cache block
constexpr int BMAX = 128;   // max cache blocks per seq
constexpr int KMAX = BMAX * BS;  // 2048

// ---------------------------------------------------------------------------
// Kernel 1: BARRIER-FREE wave-independent partial attention (round-6 body).
// One 64-lane wave owns one (s, kv-head, part) item of CHUNKW kv positions.
// No __syncthreads: wave-private LDS slice; compiler lgkmcnt handles same-wave
// ordering, so global loads are never drained by s_barrier vmcnt(0) semantics.
//
// parts=8 (CHUNKW=256). Rationale (S1 model, r7 post-mortem): k1 is near its
// HBM byte floor; the controllable cost is per-item overhead (Q loads,
// block-table loads, partial-acc round-trip, k2 combine length), all of
// which halve with parts. ~1150 uniform 256-KB work granules over 256 CUs.
// ---------------------------------------------------------------------------
template<int PARTS>
__global__ __launch_bounds__(256, 4)
void attn_wave_kernel(const float* __restrict__ q_ptr,
                      const float* __restrict__ kc,
                      const float* __restrict__ vc,
                      const int*   __restrict__ bt,
                      const int*   __restrict__ slens,
                      const float* __restrict__ slopes,
                      float* __restrict__ part_acc,
                      float* __restrict__ part_m,
                      float* __restrict__ part_l)
{
    constexpr int CHUNKW = KMAX / PARTS;   // kv positions per wave item
    constexpr int NCH    = CHUNKW / 64;    // 64-position sub-chunks
    constexpr int CPW    = CHUNKW / BS;    // kv cache blocks per item

    __shared__ float sm_p[4][G * CHUNKW];  // per-wave private score/p buffer

    const int wid  = threadIdx.x >> 6;     // wave within block (0..3)
    const int lane = threadIdx.x & 63;
    const int gw   = blockIdx.x * 4 + wid; // global wave-item id
    const int part = gw % PARTS;
    const int sh   = gw / PARTS;           // s*Hkv + h
    const int h    = sh & (Hkv - 1);
    const int s    = sh >> 3;

    const int seq_len   = slens[s];
    const int num_parts = (seq_len + CHUNKW - 1) / CHUNKW;
    if (part >= num_parts) return;         // divergent exit safe: no barriers

    float* smp = sm_p[wid];

    // Block-table entries (valid block ids even beyond seq_len; scores masked).
    int phys[CPW];
    #pragma unroll
    for (int i = 0; i < CPW; ++i) phys[i] = bt[s * BMAX + part * CPW + i];

    const float ctx  = (float)(seq_len - 1);
    const int   pos0 = part * CHUNKW;

    // ---------------- K phase ----------------
    const int o4 = lane >> 4;   // position-within-group (0..3)
    const int t  = lane & 15;   // d-chunk index: d = t*8 .. t*8+7

    const float wslope = slopes[h * G + (t & 3)];  // slope for the g this lane writes

    float4 qa[G], qb[G];
    #pragma unroll
    for (int g = 0; g < G; ++g) {
        const float* qp = q_ptr + ((size_t)(s * Hq + h * G + g) * D + t * 8);
        qa[g] = ((const float4*)qp)[0];
        qb[g] = ((const float4*)qp)[1];
    }

    #pragma unroll
    for (int c = 0; c < NCH; ++c) {
        #pragma unroll
        for (int jb = 0; jb < 4; ++jb) {
            // One kv cache block per batch; 8 float4 loads issued before use.
            const float* kbase = kc + ((((size_t)phys[c * 4 + jb] * Hkv + h) * (D / 8) + t) * BS) * 8;
            float4 kA[4], kB[4];
            #pragma unroll
            for (int j2 = 0; j2 < 4; ++j2) {
                const float* kp = kbase + (j2 * 4 + o4) * 8;
                kA[j2] = ((const float4*)kp)[0];
                kB[j2] = ((const float4*)kp)[1];
            }
            #pragma unroll
            for (int j2 = 0; j2 < 4; ++j2) {
                float sc0 = qa[0].x*kA[j2].x + qa[0].y*kA[j2].y + qa[0].z*kA[j2].z + qa[0].w*kA[j2].w
                          + qb[0].x*kB[j2].x + qb[0].y*kB[j2].y + qb[0].z*kB[j2].z + qb[0].w*kB[j2].w;
                float sc1 = qa[1].x*kA[j2].x + qa[1].y*kA[j2].y + qa[1].z*kA[j2].z + qa[1].w*kA[j2].w
                          + qb[1].x*kB[j2].x + qb[1].y*kB[j2].y + qb[1].z*kB[j2].z + qb[1].w*kB[j2].w;
                float sc2 = qa[2].x*kA[j2].x + qa[2].y*kA[j2].y + qa[2].z*kA[j2].z + qa[2].w*kA[j2].w
                          + qb[2].x*kB[j2].x + qb[2].y*kB[j2].y + qb[2].z*kB[j2].z + qb[2].w*kB[j2].w;
                float sc3 = qa[3].x*kA[j2].x + qa[3].y*kA[j2].y + qa[3].z*kA[j2].z + qa[3].w*kA[j2].w
                          + qb[3].x*kB[j2].x + qb[3].y*kB[j2].y + qb[3].z*kB[j2].z + qb[3].w*kB[j2].w;
                #pragma unroll
                for (int msk = 8; msk >= 1; msk >>= 1) {
                    sc0 += __shfl_xor(sc0, msk, 16);
                    sc1 += __shfl_xor(sc1, msk, 16);
                    sc2 += __shfl_xor(sc2, msk, 16);
                    sc3 += __shfl_xor(sc3, msk, 16);
                }
                if (t < 4) {
                    const int pl   = c * 64 + (jb * 4 + j2) * 4 + o4;  // local pos
                    const int kpos = pos0 + pl;
                    const float scv = (t == 0) ? sc0 : (t == 1) ? sc1 : (t == 2) ? sc2 : sc3;
                    smp[t * CHUNKW + pl] =
                        (kpos < seq_len) ? (SCALE_F * scv + wslope * ((float)kpos - ctx)) : NEG_INF;
                }
            }
        }
    }

    // ---------------- V prefetch (block 0) — stays in flight over softmax ---
    const int d0 = lane;                   // covers d = lane and lane + 64
    float4 vreg[2][2][4];                  // [buf][d-half][pos-quad]
    {
        const float* vb = vc + ((size_t)phys[0] * Hkv + h) * D * BS;
        #pragma unroll
        for (int c = 0; c < 4; ++c) {
            vreg[0][0][c] = ((const float4*)(vb + (size_t)d0 * BS))[c];
            vreg[0][1][c] = ((const float4*)(vb + (size_t)(d0 + 64) * BS))[c];
        }
    }

    // ---------------- softmax (LDS + width-16 shuffles, no barrier) --------
    {
        const int gS = lane >> 4;          // g this lane-group reduces
        const int u  = lane & 15;
        float* rowp = smp + gS * CHUNKW;

        float4 sv[NCH];
        float m = NEG_INF;
        #pragma unroll
        for (int w = 0; w < NCH; ++w) {
            sv[w] = ((const float4*)(rowp + u * 4 + w * 64))[0];
            m = fmaxf(m, fmaxf(fmaxf(sv[w].x, sv[w].y), fmaxf(sv[w].z, sv[w].w)));
        }
        #pragma unroll
        for (int msk = 8; msk >= 1; msk >>= 1) m = fmaxf(m, __shfl_xor(m, msk, 16));

        float l = 0.f;
        #pragma unroll
        for (int w = 0; w < NCH; ++w) {
            float4 pv;
            pv.x = __expf(sv[w].x - m);
            pv.y = __expf(sv[w].y - m);
            pv.z = __expf(sv[w].z - m);
            pv.w = __expf(sv[w].w - m);
            l += pv.x + pv.y + pv.z + pv.w;
            ((float4*)(rowp + u * 4 + w * 64))[0] = pv;
        }
        #pragma unroll
        for (int msk = 8; msk >= 1; msk >>= 1) l += __shfl_xor(l, msk, 16);

        if (u == 0) {
            part_m[(sh * PARTS + part) * G + gS] = m;
            part_l[(sh * PARTS + part) * G + gS] = l;
        }
    }

    // ---------------- PV: double-buffered V regs, p via LDS broadcast ------
    float acc0[G] = {0.f, 0.f, 0.f, 0.f};  // d = lane
    float acc1[G] = {0.f, 0.f, 0.f, 0.f};  // d = lane + 64

    #pragma unroll
    for (int i = 0; i < CPW; ++i) {
        const int cb = i & 1;
        if (i + 1 < CPW) {
            const float* vb = vc + ((size_t)phys[i + 1] * Hkv + h) * D * BS;
            #pragma unroll
            for (int c = 0; c < 4; ++c) {
                vreg[cb ^ 1][0][c] = ((const float4*)(vb + (size_t)d0 * BS))[c];
                vreg[cb ^ 1][1][c] = ((const float4*)(vb + (size_t)(d0 + 64) * BS))[c];
            }
        }
        #pragma unroll
        for (int g = 0; g < G; ++g) {
            const float4* pp = (const float4*)(smp + g * CHUNKW + i * BS);
            #pragma unroll
            for (int c = 0; c < 4; ++c) {
                const float4 p4 = pp[c];   // uniform address: LDS broadcast
                acc0[g] += p4.x * vreg[cb][0][c].x + p4.y * vreg[cb][0][c].y
                         + p4.z * vreg[cb][0][c].z + p4.w * vreg[cb][0][c].w;
                acc1[g] += p4.x * vreg[cb][1][c].x + p4.y * vreg[cb][1][c].y
                         + p4.z * vreg[cb][1][c].z + p4.w * vreg[cb][1][c].w;
            }
        }
    }

    float* outp = part_acc + (size_t)(sh * PARTS + part) * G * D;
    #pragma unroll
    for (int g = 0; g < G; ++g) {
        outp[g * D + d0]      = acc0[g];
        outp[g * D + d0 + 64] = acc1[g];
    }
}

// ---------------------------------------------------------------------------
// Kernel 2: combine partials across parts, normalize, write output.
// ---------------------------------------------------------------------------
__global__ __launch_bounds__(512)
void attn_reduce_kernel(const float* __restrict__ part_acc,
                        const float* __restrict__ part_m,
                        const float* __restrict__ part_l,
                        const int*   __restrict__ slens,
                        float* __restrict__ out,
                        int parts, int chunk)
{
    const int sh  = blockIdx.x;      // s*Hkv + h
    const int s   = sh / Hkv;
    const int tid = threadIdx.x;
    const int g   = tid >> 7;
    const int d   = tid & 127;

    const int seq_len = slens[s];
    const int np = min(parts, (seq_len + chunk - 1) / chunk);

    float M = NEG_INF;
    for (int p = 0; p < np; ++p)
        M = fmaxf(M, part_m[(sh * parts + p) * G + g]);
    float L = 0.f, acc = 0.f;
    for (int p = 0; p < np; ++p) {
        const float w = __expf(part_m[(sh * parts + p) * G + g] - M);
        L += w * part_l[(sh * parts + p) * G + g];
        acc += w * part_acc[((size_t)(sh * parts + p) * G + g) * D + d];
    }
    out[(size_t)(sh * G + g) * D + d] = acc / (L + 1e-10f);
}

extern "C" void kernel_launch(void* const* d_in, const int* in_sizes, int n_in,
                              void* d_out, int out_size, void* d_ws, size_t ws_size,
                              hipStream_t stream)
{
    const float* q   = (const float*)d_in[0];
    const float* kc  = (const float*)d_in[1];
    const float* vc  = (const float*)d_in[2];
    const int*   bt  = (const int*)d_in[3];
    const int*   sl  = (const int*)d_in[4];
    const float* slp = (const float*)d_in[5];
    // d_in[6] (query_start_len) is arange(S+1): all rows decode, identity scatter.

    auto ws_need = [](int p) {
        return (size_t)S * Hkv * p * G * (D + 2) * sizeof(float);
    };
    int parts = 8;
    while (parts > 4 && ws_need(parts) > ws_size) parts >>= 1;
    const int chunk = KMAX / parts;

    float* part_acc = (float*)d_ws;
    float* part_m   = part_acc + (size_t)S * Hkv * parts * G * D;
    float* part_l   = part_m   + (size_t)S * Hkv * parts * G;

    const dim3 grid1(S * Hkv * parts / 4);   // 4 wave-items per 256-thread block
    switch (parts) {
    case 8:  attn_wave_kernel<8> <<<grid1, 256, 0, stream>>>(q, kc, vc, bt, sl, slp, part_acc, part_m, part_l); break;
    default: attn_wave_kernel<4> <<<grid1, 256, 0, stream>>>(q, kc, vc, bt, sl, slp, part_acc, part_m, part_l); break;
    }
    attn_reduce_kernel<<<S * Hkv, 512, 0, stream>>>(
        part_acc, part_m, part_l, sl, (float*)d_out, parts, chunk);
}